// Round 6
// baseline (258.992 us; speedup 1.0000x reference)
//
#include <hip/hip_runtime.h>

#define DEVINL __device__ __forceinline__

// lower-tri packed index, requires i >= j
#define TIX(i, j) ((i) * ((i) + 1) / 2 + (j))
// symmetric access (compile-time resolved under full unroll)
#define SYM(arr, i, j) ((i) >= (j) ? arr[TIX(i, j)] : arr[TIX(j, i)])

// Pin VMEM issue order across this point (loads/stores cannot cross).
#define MEMFENCE() asm volatile("" ::: "memory")
// Counted wait: block until <= n VMEM ops outstanding. Memory clobber keeps
// subsequent ds_reads from hoisting above it (rule #18 concerns reg-only ops,
// ds_read is a memory op and is ordered by the clobber).
#define VMCNT(n) asm volatile("s_waitcnt vmcnt(" #n ")" ::: "memory")

// Async global->LDS DMA, 16B per lane. LDS dest = uniform base + lane*16
// (linear!), global src is PER-LANE -> swizzle the source to get a swizzled
// LDS image (guide #21 / m173).
#define GLOAD16(gsrc, ldst)                                        \
    __builtin_amdgcn_global_load_lds(                              \
        (const __attribute__((address_space(1))) void*)(gsrc),     \
        (__attribute__((address_space(3))) void*)(ldst), 16, 0, 0)

DEVINL void inv4(const float* m, float* inv) {
    float s0 = m[0] * m[5] - m[1] * m[4];
    float s1 = m[0] * m[6] - m[2] * m[4];
    float s2 = m[0] * m[7] - m[3] * m[4];
    float s3 = m[1] * m[6] - m[2] * m[5];
    float s4 = m[1] * m[7] - m[3] * m[5];
    float s5 = m[2] * m[7] - m[3] * m[6];
    float c5 = m[10] * m[15] - m[11] * m[14];
    float c4 = m[9] * m[15] - m[11] * m[13];
    float c3 = m[9] * m[14] - m[10] * m[13];
    float c2 = m[8] * m[15] - m[11] * m[12];
    float c1 = m[8] * m[14] - m[10] * m[12];
    float c0 = m[8] * m[13] - m[9] * m[12];
    float det = s0 * c5 - s1 * c4 + s2 * c3 + s3 * c2 - s4 * c1 + s5 * c0;
    float id = 1.0f / det;
    inv[0]  = ( m[5] * c5 - m[6] * c4 + m[7] * c3) * id;
    inv[1]  = (-m[1] * c5 + m[2] * c4 - m[3] * c3) * id;
    inv[2]  = ( m[13] * s5 - m[14] * s4 + m[15] * s3) * id;
    inv[3]  = (-m[9] * s5 + m[10] * s4 - m[11] * s3) * id;
    inv[4]  = (-m[4] * c5 + m[6] * c2 - m[7] * c1) * id;
    inv[5]  = ( m[0] * c5 - m[2] * c2 + m[3] * c1) * id;
    inv[6]  = (-m[12] * s5 + m[14] * s2 - m[15] * s1) * id;
    inv[7]  = ( m[8] * s5 - m[10] * s2 + m[11] * s1) * id;
    inv[8]  = ( m[4] * c4 - m[5] * c2 + m[7] * c0) * id;
    inv[9]  = (-m[0] * c4 + m[1] * c2 - m[3] * c0) * id;
    inv[10] = ( m[12] * s4 - m[13] * s2 + m[15] * s0) * id;
    inv[11] = (-m[8] * s4 + m[9] * s2 - m[11] * s0) * id;
    inv[12] = (-m[4] * c3 + m[5] * c1 - m[6] * c0) * id;
    inv[13] = ( m[0] * c3 - m[1] * c1 + m[2] * c0) * id;
    inv[14] = (-m[12] * s3 + m[13] * s1 - m[14] * s0) * id;
    inv[15] = ( m[8] * s3 - m[9] * s1 + m[10] * s0) * id;
}

// 64-thread (1-wave) blocks, 1 batch/thread. ALL big inputs prefetched in one
// 49-instruction global_load_lds burst (no VGPR round trip, no barriers),
// consumed behind counted vmcnt waits so every unpack/compute phase overlaps
// the remaining loads' flight. Source-address XOR swizzle (involution q^(b&7))
// makes the linear DMA image read back conflict-light (8-quad spread).
// VMEM issue order (fence-pinned): s[2] pn[9] P[16] F[16] H[8] = 51 ops, then
// z+mn [6] issued mid-kernel. Waits: pn<=40(use 38), P<=24(22), F<=8(6), 0.
__global__ __launch_bounds__(64) void ekf_kernel(
    const float* __restrict__ meas,   // (B,4)
    const float* __restrict__ state,  // (B,8)
    const float* __restrict__ Pin,    // (B,8,8) symmetric
    const float* __restrict__ Fin,    // (B,8,8)
    const float* __restrict__ Hin,    // (B,4,8)
    const float* __restrict__ pnin,   // (B,36)
    const float* __restrict__ mnin,   // (B,10)
    float* __restrict__ out_pred,     // (B,4)
    float* __restrict__ out_state,    // (B,8)
    float* __restrict__ out_cov)      // (B,8,8)
{
    const int t  = threadIdx.x;
    const int bb = blockIdx.x * 64;
    const int b  = bb + t;
    const int tx = t & 7;

    __shared__ float4 arena[3136];    // 50,176 B -> 3 blocks/CU
    float4* pn4 = arena;              // [0, 576)
    float4* P4  = arena + 576;        // [576, 1600)
    float4* F4  = arena + 1600;       // [1600, 2624)
    float4* H4  = arena + 2624;       // [2624, 3136)
    float4* st4 = arena + 576;        // reuse P region for out_state staging
    float4* cv4 = arena + 1600;       // reuse F region for out_cov staging

    // ---------------- issue: s first (cheap compiler wait later) ----------------
    float s[8];
    {
        const float4* g = reinterpret_cast<const float4*>(state) + (size_t)b * 2;
        float4 a = g[0], c = g[1];
        s[0] = a.x; s[1] = a.y; s[2] = a.z; s[3] = a.w;
        s[4] = c.x; s[5] = c.y; s[6] = c.z; s[7] = c.w;
    }
    MEMFENCE();

    // ---------------- issue burst: 49 global_load_lds ----------------
    {   // pn: identity layout (stride 144B self-spreads banks)
        const float4* g = reinterpret_cast<const float4*>(pnin) + (size_t)bb * 9;
        #pragma unroll
        for (int i = 0; i < 9; ++i)
            GLOAD16(g + (i * 64 + t), pn4 + i * 64);
    }
    {   // P: source-swizzled q^(batch&7)
        const float4* g = reinterpret_cast<const float4*>(Pin) + (size_t)bb * 16;
        #pragma unroll
        for (int i = 0; i < 16; ++i) {
            int f = i * 64 + t, bq = f >> 4, qp = f & 15;
            GLOAD16(g + ((bq << 4) | (qp ^ (bq & 7))), P4 + i * 64);
        }
    }
    {   // F: source-swizzled
        const float4* g = reinterpret_cast<const float4*>(Fin) + (size_t)bb * 16;
        #pragma unroll
        for (int i = 0; i < 16; ++i) {
            int f = i * 64 + t, bq = f >> 4, qp = f & 15;
            GLOAD16(g + ((bq << 4) | (qp ^ (bq & 7))), F4 + i * 64);
        }
    }
    {   // H: source-swizzled
        const float4* g = reinterpret_cast<const float4*>(Hin) + (size_t)bb * 8;
        #pragma unroll
        for (int i = 0; i < 8; ++i) {
            int f = i * 64 + t, bq = f >> 3, qp = f & 7;
            GLOAD16(g + ((bq << 3) | (qp ^ (bq & 7))), H4 + i * 64);
        }
    }
    MEMFENCE();

    // ---------------- pn ready: Q = Lq Lq^T ----------------
    VMCNT(38);
    float Pn[36];  // becomes new_state_cov
    {
        float Lq[36];
        #pragma unroll
        for (int q = 0; q < 9; ++q) {
            float4 v = pn4[t * 9 + q];
            Lq[4 * q] = v.x; Lq[4 * q + 1] = v.y; Lq[4 * q + 2] = v.z; Lq[4 * q + 3] = v.w;
        }
        #pragma unroll
        for (int i = 0; i < 8; ++i)
            #pragma unroll
            for (int j = 0; j <= i; ++j) {
                float acc = 0.f;
                #pragma unroll
                for (int k = 0; k <= j; ++k)
                    acc += Lq[TIX(i, k)] * Lq[TIX(j, k)];
                Pn[TIX(i, j)] = acc;
            }
    }

    // ---------------- P ready: unpack packed lower-tri ----------------
    VMCNT(22);
    float Ps[36];
    #pragma unroll
    for (int q = 0; q < 16; ++q) {
        float4 v = P4[t * 16 + (q ^ tx)];
        const int row = q >> 1, c0 = (q & 1) * 4;
        if (c0 + 0 <= row) Ps[TIX(row, c0 + 0)] = v.x;
        if (c0 + 1 <= row) Ps[TIX(row, c0 + 1)] = v.y;
        if (c0 + 2 <= row) Ps[TIX(row, c0 + 2)] = v.z;
        if (c0 + 3 <= row) Ps[TIX(row, c0 + 3)] = v.w;
    }

    // ---------------- F ready: unpack ----------------
    VMCNT(6);
    float Fm[64];
    #pragma unroll
    for (int q = 0; q < 16; ++q) {
        float4 v = F4[t * 16 + (q ^ tx)];
        Fm[4 * q + 0] = v.x; Fm[4 * q + 1] = v.y;
        Fm[4 * q + 2] = v.z; Fm[4 * q + 3] = v.w;
    }

    // issue z + mn now (latency hides under predict compute)
    MEMFENCE();
    float4 z = *(reinterpret_cast<const float4*>(meas) + b);
    float Lr[10];
    {
        const float2* g = reinterpret_cast<const float2*>(mnin) + (size_t)b * 5;
        #pragma unroll
        for (int p = 0; p < 5; ++p) {
            float2 v = g[p];
            Lr[2 * p] = v.x; Lr[2 * p + 1] = v.y;
        }
    }
    MEMFENCE();

    // ---------------- predict: ns = F s; Pn += F P F^T ----------------
    float ns[8];
    #pragma unroll
    for (int i = 0; i < 8; ++i) {
        float acc = 0.f;
        #pragma unroll
        for (int j = 0; j < 8; ++j) acc += Fm[i * 8 + j] * s[j];
        ns[i] = acc;
    }
    #pragma unroll
    for (int l = 0; l < 8; ++l) {
        float gcol[8];  // gcol[j] = (P F^T)[j][l]
        #pragma unroll
        for (int j = 0; j < 8; ++j) {
            float acc = 0.f;
            #pragma unroll
            for (int k = 0; k < 8; ++k) acc += SYM(Ps, j, k) * Fm[l * 8 + k];
            gcol[j] = acc;
        }
        #pragma unroll
        for (int i = l; i < 8; ++i) {
            float acc = Pn[TIX(i, l)];
            #pragma unroll
            for (int j = 0; j < 8; ++j) acc += Fm[i * 8 + j] * gcol[j];
            Pn[TIX(i, l)] = acc;
        }
    }
    // Fm, Ps, s dead

    // ---------------- H + z + mn ready ----------------
    VMCNT(0);
    float Hm[32];
    #pragma unroll
    for (int q = 0; q < 8; ++q) {
        float4 v = H4[t * 8 + (q ^ tx)];
        Hm[4 * q + 0] = v.x; Hm[4 * q + 1] = v.y;
        Hm[4 * q + 2] = v.z; Hm[4 * q + 3] = v.w;
    }

    // residual + prediction out (direct, 16B/lane coalesced)
    float res[4];
    {
        float pr[4];
        #pragma unroll
        for (int i = 0; i < 4; ++i) {
            float acc = 0.f;
            #pragma unroll
            for (int j = 0; j < 8; ++j) acc += Hm[i * 8 + j] * ns[j];
            pr[i] = acc;
        }
        res[0] = z.x - pr[0]; res[1] = z.y - pr[1];
        res[2] = z.z - pr[2]; res[3] = z.w - pr[3];
        *(reinterpret_cast<float4*>(out_pred) + b) =
            make_float4(pr[0], pr[1], pr[2], pr[3]);
    }

    // HP = H newP (4x8); PHt = HP^T by symmetry
    float HP[32];
    #pragma unroll
    for (int i = 0; i < 4; ++i)
        #pragma unroll
        for (int k = 0; k < 8; ++k) {
            float acc = 0.f;
            #pragma unroll
            for (int j = 0; j < 8; ++j) acc += Hm[i * 8 + j] * SYM(Pn, j, k);
            HP[i * 8 + k] = acc;
        }

    // S = HP H^T + R -> inverse
    float Si[16];
    {
        float Sf[16];
        #pragma unroll
        for (int i = 0; i < 4; ++i)
            #pragma unroll
            for (int l = 0; l <= i; ++l) {
                float acc = 0.f;
                #pragma unroll
                for (int k = 0; k < 8; ++k) acc += HP[i * 8 + k] * Hm[l * 8 + k];
                Sf[i * 4 + l] = acc;
                Sf[l * 4 + i] = acc;
            }
        #pragma unroll
        for (int i = 0; i < 4; ++i)
            #pragma unroll
            for (int j = 0; j <= i; ++j) {
                float acc = 0.f;
                #pragma unroll
                for (int k = 0; k <= j; ++k)
                    acc += Lr[TIX(i, k)] * Lr[TIX(j, k)];
                Sf[i * 4 + j] += acc;
                if (i != j) Sf[j * 4 + i] += acc;
            }
        inv4(Sf, Si);
    }
    // Hm dead (after Sf)

    // upd_state = ns + HP^T (Si res)
    float us[8];
    {
        float w[4];
        #pragma unroll
        for (int a = 0; a < 4; ++a) {
            float acc = 0.f;
            #pragma unroll
            for (int c = 0; c < 4; ++c) acc += Si[a * 4 + c] * res[c];
            w[a] = acc;
        }
        #pragma unroll
        for (int i = 0; i < 8; ++i) {
            float acc = ns[i];
            #pragma unroll
            for (int a = 0; a < 4; ++a) acc += HP[a * 8 + i] * w[a];
            us[i] = acc;
        }
    }

    // stage upd_state out (pad-3 layout through reused P region)
    st4[t * 3 + 0] = make_float4(us[0], us[1], us[2], us[3]);
    st4[t * 3 + 1] = make_float4(us[4], us[5], us[6], us[7]);
    __syncthreads();
    {
        float4* g = reinterpret_cast<float4*>(out_state) + (size_t)bb * 2;
        #pragma unroll
        for (int i = 0; i < 2; ++i) {
            int f = i * 64 + t;
            g[f] = st4[(f >> 1) * 3 + (f & 1)];
        }
    }

    // upd_cov = Pn - HP^T (Si HP), in place (symmetric)
    {
        float M[32];  // M = Si HP (4x8)
        #pragma unroll
        for (int a = 0; a < 4; ++a)
            #pragma unroll
            for (int j = 0; j < 8; ++j) {
                float acc = 0.f;
                #pragma unroll
                for (int c = 0; c < 4; ++c) acc += Si[a * 4 + c] * HP[c * 8 + j];
                M[a * 8 + j] = acc;
            }
        #pragma unroll
        for (int i = 0; i < 8; ++i)
            #pragma unroll
            for (int l = 0; l <= i; ++l) {
                float acc = Pn[TIX(i, l)];
                #pragma unroll
                for (int a = 0; a < 4; ++a) acc -= HP[a * 8 + i] * M[a * 8 + l];
                Pn[TIX(i, l)] = acc;
            }
    }

    // cov out: two row-halves through reused F region, mirrored from packed
    #pragma unroll
    for (int h = 0; h < 2; ++h) {
        __syncthreads();
        #pragma unroll
        for (int r = 0; r < 4; ++r) {
            const int i = 4 * h + r;
            cv4[t * 9 + 2 * r + 0] = make_float4(SYM(Pn, i, 0), SYM(Pn, i, 1),
                                                 SYM(Pn, i, 2), SYM(Pn, i, 3));
            cv4[t * 9 + 2 * r + 1] = make_float4(SYM(Pn, i, 4), SYM(Pn, i, 5),
                                                 SYM(Pn, i, 6), SYM(Pn, i, 7));
        }
        __syncthreads();
        {
            float4* g = reinterpret_cast<float4*>(out_cov) + (size_t)bb * 16;
            #pragma unroll
            for (int i = 0; i < 8; ++i) {
                int fl = i * 64 + t;
                int bq = fl >> 3, q = fl & 7;
                g[bq * 16 + 8 * h + q] = cv4[bq * 9 + q];
            }
        }
    }
}

extern "C" void kernel_launch(void* const* d_in, const int* in_sizes, int n_in,
                              void* d_out, int out_size, void* d_ws, size_t ws_size,
                              hipStream_t stream) {
    const float* meas  = (const float*)d_in[0];
    const float* state = (const float*)d_in[1];
    const float* Pin   = (const float*)d_in[2];
    const float* Fin   = (const float*)d_in[3];
    const float* Hin   = (const float*)d_in[4];
    const float* pn    = (const float*)d_in[5];
    const float* mn    = (const float*)d_in[6];

    const int B = in_sizes[1] / 8;  // state is (B, 8); B = 262144

    float* out = (float*)d_out;
    float* out_pred  = out;                       // B*4
    float* out_state = out + (size_t)B * 4;       // B*8
    float* out_cov   = out + (size_t)B * 12;      // B*64

    dim3 block(64);
    dim3 grid(B / 64);
    ekf_kernel<<<grid, block, 0, stream>>>(meas, state, Pin, Fin, Hin, pn, mn,
                                           out_pred, out_state, out_cov);
}